// Round 15
// baseline (8729.865 us; speedup 1.0000x reference)
//
#include <hip/hip_runtime.h>
#include <hip/hip_bf16.h>
#include <stdint.h>

#define M_TOTAL 8192
#define K_TOTAL 4096
#define N_TOTAL 16384
#define BM 256
#define BN 256
#define KT 64                          // 64 K-tiles of 64 (i8: one MFMA eats K=64)
#define TILE_B 16384                   // bytes per 256-row block per K-tile (256 x 64 x 1B)
#define BUF_S 32768                    // LDS buffer: A 16KB + B 16KB
#define NBUF 2                         // 64KB LDS -> 2 blocks/CU (the experiment)

typedef int i32x4 __attribute__((ext_vector_type(4)));

static __device__ __forceinline__ void async16(const void* g, void* l) {
    __builtin_amdgcn_global_load_lds((const __attribute__((address_space(1))) unsigned int*)g,
                                     (__attribute__((address_space(3))) unsigned int*)l,
                                     16, 0, 0);
}

// ---------------- scale + packing kernels (unchanged from round 13/14) ----------------
// Packed i8 layout per 256-row block (1MB): [kt 0..63][f 0..15][lane 0..63][16B]
// element (row, k): f=(row>>4)&15, lane=(row&15)|(((k>>4)&3)<<4), byte=k&15.

__global__ __launch_bounds__(256) void rowmax_kernel(const float* __restrict__ x,
                                                     float* __restrict__ sx,
                                                     float* __restrict__ invx) {
    int row = blockIdx.x * 4 + (threadIdx.x >> 6);
    int lane = threadIdx.x & 63;
    const float4* p = reinterpret_cast<const float4*>(x + (size_t)row * K_TOTAL) + lane;
    float m = 0.f;
    #pragma unroll
    for (int i = 0; i < 16; ++i) {
        float4 v = p[i * 64];
        m = fmaxf(m, fmaxf(fmaxf(fabsf(v.x), fabsf(v.y)), fmaxf(fabsf(v.z), fabsf(v.w))));
    }
    #pragma unroll
    for (int off = 32; off; off >>= 1) m = fmaxf(m, __shfl_xor(m, off, 64));
    if (lane == 0) {
        m = fmaxf(m, 1e-20f);
        sx[row]   = m / 127.f;
        invx[row] = 127.f / m;
    }
}

__global__ __launch_bounds__(256) void cvt_x_pack(const float* __restrict__ x,
                                                  const float* __restrict__ invx,
                                                  char* __restrict__ xq) {
    size_t j = (size_t)blockIdx.x * 256 + threadIdx.x;   // 16 output bytes each
    int mt = (int)(j >> 16);           // 65536 threads per 256-row block
    int j2 = (int)(j & 65535);
    int kt = j2 >> 10;
    int f  = (j2 >> 6) & 15;
    int l  = j2 & 63;
    int r  = mt * 256 + f * 16 + (l & 15);
    int k0 = kt * 64 + ((l >> 4) << 4);
    float is = invx[r];
    const float4* s = reinterpret_cast<const float4*>(x + (size_t)r * K_TOTAL + k0);
    int q[16];
    #pragma unroll
    for (int v4 = 0; v4 < 4; ++v4) {
        float4 v = s[v4];
        q[v4 * 4 + 0] = (int)__builtin_rintf(v.x * is);
        q[v4 * 4 + 1] = (int)__builtin_rintf(v.y * is);
        q[v4 * 4 + 2] = (int)__builtin_rintf(v.z * is);
        q[v4 * 4 + 3] = (int)__builtin_rintf(v.w * is);
    }
    int4 d;
    d.x = (q[0]&0xff) | ((q[1]&0xff)<<8) | ((q[2]&0xff)<<16) | (q[3]<<24);
    d.y = (q[4]&0xff) | ((q[5]&0xff)<<8) | ((q[6]&0xff)<<16) | (q[7]<<24);
    d.z = (q[8]&0xff) | ((q[9]&0xff)<<8) | ((q[10]&0xff)<<16) | (q[11]<<24);
    d.w = (q[12]&0xff) | ((q[13]&0xff)<<8) | ((q[14]&0xff)<<16) | (q[15]<<24);
    *reinterpret_cast<int4*>(xq + j * 16) = d;
}

__global__ __launch_bounds__(256) void cvt_w_pack(const int* __restrict__ w,
                                                  char* __restrict__ wq) {
    size_t j = (size_t)blockIdx.x * 256 + threadIdx.x;
    int nt = (int)(j >> 16);
    int j2 = (int)(j & 65535);
    int kt = j2 >> 10;
    int f  = (j2 >> 6) & 15;
    int l  = j2 & 63;
    int r  = nt * 256 + f * 16 + (l & 15);
    int k0 = kt * 64 + ((l >> 4) << 4);
    const int4* s = reinterpret_cast<const int4*>(w + (size_t)r * K_TOTAL + k0);
    int4 v0 = s[0], v1 = s[1], v2 = s[2], v3 = s[3];
    int4 d;
    d.x = (v0.x&0xff) | ((v0.y&0xff)<<8) | ((v0.z&0xff)<<16) | (v0.w<<24);
    d.y = (v1.x&0xff) | ((v1.y&0xff)<<8) | ((v1.z&0xff)<<16) | (v1.w<<24);
    d.z = (v2.x&0xff) | ((v2.y&0xff)<<8) | ((v2.z&0xff)<<16) | (v2.w<<24);
    d.w = (v3.x&0xff) | ((v3.y&0xff)<<8) | ((v3.z&0xff)<<16) | (v3.w<<24);
    *reinterpret_cast<int4*>(wq + j * 16) = d;
}

// ---------------- GEMM: i8, 2-buffer LDS (64KB) -> 2 blocks/CU ----------------
// Window w (set s = w&1): STG(tile w+2 -> buf w&1); 12 ds_reads of tile w+1
// <- buf (w+1)&1 into set ~s; 32 mfma_i32_16x16x64_i8 on set s; LGKM0;
// VMC0; barrier.
// Safety: stage(w+2) overwrites buf w&1 whose last readers (tile w, read at
// w-1) retired via LGKM0 before w-1's barrier. Reads(w+1) target buf (w+1)&1
// staged at w-1 and certified by VMC0+bar at w-1 (stage latency ~300cy L2
// hides inside the ~2500cy window). The point of NBUF=2: 64KB LDS fits TWO
// blocks per CU -- independent blocks have no shared barrier, so one block's
// MFMA cluster overlaps the other's LDS bursts (m97/m114 mechanism).

#define BAR()    { asm volatile("" ::: "memory"); __builtin_amdgcn_s_barrier(); asm volatile("" ::: "memory"); }
#define LGKM0()  asm volatile("s_waitcnt lgkmcnt(0)" ::: "memory")
#define VMC4()   asm volatile("s_waitcnt vmcnt(4)" ::: "memory")
#define VMC0()   asm volatile("s_waitcnt vmcnt(0)" ::: "memory")
#define PRIO1()  __builtin_amdgcn_s_setprio(1)
#define PRIO0()  __builtin_amdgcn_s_setprio(0)
#define SCHEDB() __builtin_amdgcn_sched_barrier(0)

#define STG(ts, so) { \
    async16(aS + (size_t)(ts)*TILE_B + tid*16,        ldsc + (so) + tid*16); \
    async16(aS + (size_t)(ts)*TILE_B + 8192 + tid*16, ldsc + (so) + 8192 + tid*16); \
    async16(bS + (size_t)(ts)*TILE_B + tid*16,        ldsc + (so) + 16384 + tid*16); \
    async16(bS + (size_t)(ts)*TILE_B + 8192 + tid*16, ldsc + (so) + 24576 + tid*16); }

#define RDF0(bo) { \
    _Pragma("unroll") for (int ni = 0; ni < 4; ++ni) bfr0[ni] = *(const i32x4*)(bRd + (bo) + ni * 1024); \
    _Pragma("unroll") for (int mi = 0; mi < 8; ++mi) afr0[mi] = *(const i32x4*)(aRd + (bo) + mi * 1024); }

#define RDF1(bo) { \
    _Pragma("unroll") for (int ni = 0; ni < 4; ++ni) bfr1[ni] = *(const i32x4*)(bRd + (bo) + ni * 1024); \
    _Pragma("unroll") for (int mi = 0; mi < 8; ++mi) afr1[mi] = *(const i32x4*)(aRd + (bo) + mi * 1024); }

#define MMA0() { PRIO1(); \
    _Pragma("unroll") for (int mi = 0; mi < 8; ++mi) { _Pragma("unroll") \
        for (int ni = 0; ni < 4; ++ni) \
            acc[mi][ni] = __builtin_amdgcn_mfma_i32_16x16x64_i8(afr0[mi], bfr0[ni], acc[mi][ni], 0, 0, 0); } \
    PRIO0(); }

#define MMA1() { PRIO1(); \
    _Pragma("unroll") for (int mi = 0; mi < 8; ++mi) { _Pragma("unroll") \
        for (int ni = 0; ni < 4; ++ni) \
            acc[mi][ni] = __builtin_amdgcn_mfma_i32_16x16x64_i8(afr1[mi], bfr1[ni], acc[mi][ni], 0, 0, 0); } \
    PRIO0(); }

#define WIN(st, sb, rb, RDFx, MMAx) { \
    STG(st, sb); \
    RDFx(rb); \
    SCHEDB(); \
    MMAx(); \
    SCHEDB(); \
    LGKM0(); VMC0(); BAR(); }

__global__ __launch_bounds__(512, 4) void gemm_kernel(const char* __restrict__ A,
                                                      const char* __restrict__ B,
                                                      const float* __restrict__ scale,
                                                      const float* __restrict__ sx,
                                                      float* __restrict__ out) {
    extern __shared__ char ldsc[];
    const int tid  = threadIdx.x;
    const int lane = tid & 63;
    const int wave = tid >> 6;
    const int wm = wave >> 2;          // 0..1
    const int wn = wave & 3;           // 0..3

    // XCD-aware bijective swizzle (2048 blocks, 8 XCDs, 256-block chunks);
    // mt fastest within chunk -> co-resident blocks/XCD share B-panels.
    int orig = blockIdx.x;
    int swzid = (orig & 7) * 256 + (orig >> 3);
    int mt = swzid & 31;
    int nt = swzid >> 5;

    const char* aS = A + (size_t)mt * (KT * TILE_B);
    const char* bS = B + (size_t)nt * (KT * TILE_B);

    // fragment read bases: stride-1 1KB wave reads (uniform base + lane*16)
    const char* aRd = ldsc + wm * 8192 + lane * 16;           // + bo + mi*1024
    const char* bRd = ldsc + 16384 + wn * 4096 + lane * 16;   // + bo + ni*1024

    i32x4 acc[8][4];
    #pragma unroll
    for (int mi = 0; mi < 8; ++mi)
        #pragma unroll
        for (int ni = 0; ni < 4; ++ni)
            acc[mi][ni] = (i32x4){0, 0, 0, 0};

    i32x4 afr0[8], bfr0[4], afr1[8], bfr1[4];

    // prologue: stage tile0->buf0, tile1->buf1; VMC4 certifies tile0 (tile1's
    // 4 loads stay in flight); BAR; read tile0 -> set0; LGKM0; BAR (all waves'
    // tile-0 reads retired before window 0 overwrites buf0).
    STG(0, 0); STG(1, BUF_S);
    VMC4();
    BAR();
    RDF0(0);
    LGKM0();
    VMC0();                    // tile1 certified for reads at window 0
    BAR();

    // windows 0..61 (stage tiles 2..63), unroll x2
    for (int w = 0; w < 62; w += 2) {
        WIN(w + 2, 0,     BUF_S, RDF1, MMA0);   // w even: stage->buf0, rd t+1<-buf1, mfma t
        WIN(w + 3, BUF_S, 0,     RDF0, MMA1);   // w odd:  stage->buf1, rd t+2<-buf0, mfma t+1
    }
    // window 62 (set0): rd tile 63 <- buf1; mfma 62.
    RDF1(BUF_S);
    SCHEDB();
    MMA0();
    SCHEDB();
    // window 63 (set1): mfma 63 (compiler waits on set1's reads).
    MMA1();

    // epilogue: D row=(lane>>4)*4+j, col=lane&15 (shape-determined);
    // out = acc * sx[row] * sw[col]
    int m0 = mt * BM, n0 = nt * BN;
    int col0 = n0 + wn * 64 + (lane & 15);
    int row0 = m0 + wm * 128 + ((lane >> 4) << 2);
    float swv[4];
    #pragma unroll
    for (int ni = 0; ni < 4; ++ni) swv[ni] = scale[col0 + ni * 16];
    #pragma unroll
    for (int mi = 0; mi < 8; ++mi) {
        #pragma unroll
        for (int j = 0; j < 4; ++j) {
            int r = row0 + mi * 16 + j;
            float sr = sx[r];
            #pragma unroll
            for (int ni = 0; ni < 4; ++ni) {
                out[(size_t)r * N_TOTAL + (col0 + ni * 16)] = (float)acc[mi][ni][j] * sr * swv[ni];
            }
        }
    }
}

// ---------------- fallback ----------------

__global__ __launch_bounds__(256) void naive_kernel(const float* __restrict__ x, const int* __restrict__ w,
                                                    const float* __restrict__ scale, float* __restrict__ out) {
    int n = blockIdx.x * 256 + threadIdx.x;
    int m = blockIdx.y;
    const float* xr = x + (size_t)m * K_TOTAL;
    const int*   wr = w + (size_t)n * K_TOTAL;
    float acc = 0.f;
    for (int k = 0; k < K_TOTAL; k += 4) {
        float4 xv = *(const float4*)(xr + k);
        int4   wv = *(const int4*)(wr + k);
        acc += xv.x * (float)wv.x + xv.y * (float)wv.y + xv.z * (float)wv.z + xv.w * (float)wv.w;
    }
    out[(size_t)m * N_TOTAL + n] = acc * scale[n];
}

extern "C" void kernel_launch(void* const* d_in, const int* in_sizes, int n_in,
                              void* d_out, int out_size, void* d_ws, size_t ws_size,
                              hipStream_t stream) {
    const float* x     = (const float*)d_in[0];
    const int*   w     = (const int*)d_in[1];
    const float* scale = (const float*)d_in[2];
    float* out = (float*)d_out;

    const size_t xq_bytes = (size_t)M_TOTAL * K_TOTAL;       // 32MB
    const size_t wq_bytes = (size_t)N_TOTAL * K_TOTAL;       // 64MB
    const size_t sx_bytes = (size_t)M_TOTAL * 4;             // 32KB

    if (ws_size >= xq_bytes + wq_bytes + 2 * sx_bytes) {
        char*  xq   = (char*)d_ws;
        char*  wq   = (char*)d_ws + xq_bytes;
        float* sx   = (float*)((char*)d_ws + xq_bytes + wq_bytes);
        float* invx = sx + M_TOTAL;
        (void)hipFuncSetAttribute((const void*)gemm_kernel,
                                  hipFuncAttributeMaxDynamicSharedMemorySize, NBUF * BUF_S);
        rowmax_kernel<<<M_TOTAL / 4, 256, 0, stream>>>(x, sx, invx);
        cvt_x_pack<<<(M_TOTAL / 256) * (K_TOTAL / 16) , 256, 0, stream>>>(x, invx, xq);
        cvt_w_pack<<<(N_TOTAL / 256) * (K_TOTAL / 16), 256, 0, stream>>>(w, wq);
        gemm_kernel<<<(M_TOTAL / BM) * (N_TOTAL / BN), 512, NBUF * BUF_S, stream>>>(xq, wq, scale, sx, out);
    } else {
        dim3 g(N_TOTAL / 256, M_TOTAL);
        naive_kernel<<<g, 256, 0, stream>>>(x, w, scale, out);
    }
}

// Round 16
// 865.642 us; speedup vs baseline: 10.0848x; 10.0848x over previous
//
#include <hip/hip_runtime.h>
#include <hip/hip_bf16.h>
#include <stdint.h>

#define M_TOTAL 8192
#define K_TOTAL 4096
#define N_TOTAL 16384
#define BM 256
#define BN 128
#define KT 64                          // 64 K-tiles of 64 (i8: one MFMA eats K=64)
#define TILE_B 16384                   // bytes per 256-row block per K-tile (256 x 64 x 1B)
#define BUF_S 24576                    // LDS buffer: A 16KB + B 8KB
#define NBUF 2                         // 48KB LDS + 4-wave blocks -> 2 blocks/CU

typedef int i32x4 __attribute__((ext_vector_type(4)));

static __device__ __forceinline__ void async16(const void* g, void* l) {
    __builtin_amdgcn_global_load_lds((const __attribute__((address_space(1))) unsigned int*)g,
                                     (__attribute__((address_space(3))) unsigned int*)l,
                                     16, 0, 0);
}

// ---------------- scale + packing kernels (layouts unchanged since r13) ----------------
// Packed i8 layout per 256-row block (1MB): [kt 0..63][f 0..15][lane 0..63][16B]
// element (row, k): f=(row>>4)&15, lane=(row&15)|(((k>>4)&3)<<4), byte=k&15.
// A B-block of 128 rows = half a 256-row block: rows 0-127 are f 0..7 (first
// 8KB of each kt chunk), rows 128-255 are f 8..15 (second 8KB) -> contiguous.

__global__ __launch_bounds__(256) void rowmax_kernel(const float* __restrict__ x,
                                                     float* __restrict__ sx,
                                                     float* __restrict__ invx) {
    int row = blockIdx.x * 4 + (threadIdx.x >> 6);
    int lane = threadIdx.x & 63;
    const float4* p = reinterpret_cast<const float4*>(x + (size_t)row * K_TOTAL) + lane;
    float m = 0.f;
    #pragma unroll
    for (int i = 0; i < 16; ++i) {
        float4 v = p[i * 64];
        m = fmaxf(m, fmaxf(fmaxf(fabsf(v.x), fabsf(v.y)), fmaxf(fabsf(v.z), fabsf(v.w))));
    }
    #pragma unroll
    for (int off = 32; off; off >>= 1) m = fmaxf(m, __shfl_xor(m, off, 64));
    if (lane == 0) {
        m = fmaxf(m, 1e-20f);
        sx[row]   = m / 127.f;
        invx[row] = 127.f / m;
    }
}

__global__ __launch_bounds__(256) void cvt_x_pack(const float* __restrict__ x,
                                                  const float* __restrict__ invx,
                                                  char* __restrict__ xq) {
    size_t j = (size_t)blockIdx.x * 256 + threadIdx.x;   // 16 output bytes each
    int mt = (int)(j >> 16);           // 65536 threads per 256-row block
    int j2 = (int)(j & 65535);
    int kt = j2 >> 10;
    int f  = (j2 >> 6) & 15;
    int l  = j2 & 63;
    int r  = mt * 256 + f * 16 + (l & 15);
    int k0 = kt * 64 + ((l >> 4) << 4);
    float is = invx[r];
    const float4* s = reinterpret_cast<const float4*>(x + (size_t)r * K_TOTAL + k0);
    int q[16];
    #pragma unroll
    for (int v4 = 0; v4 < 4; ++v4) {
        float4 v = s[v4];
        q[v4 * 4 + 0] = (int)__builtin_rintf(v.x * is);
        q[v4 * 4 + 1] = (int)__builtin_rintf(v.y * is);
        q[v4 * 4 + 2] = (int)__builtin_rintf(v.z * is);
        q[v4 * 4 + 3] = (int)__builtin_rintf(v.w * is);
    }
    int4 d;
    d.x = (q[0]&0xff) | ((q[1]&0xff)<<8) | ((q[2]&0xff)<<16) | (q[3]<<24);
    d.y = (q[4]&0xff) | ((q[5]&0xff)<<8) | ((q[6]&0xff)<<16) | (q[7]<<24);
    d.z = (q[8]&0xff) | ((q[9]&0xff)<<8) | ((q[10]&0xff)<<16) | (q[11]<<24);
    d.w = (q[12]&0xff) | ((q[13]&0xff)<<8) | ((q[14]&0xff)<<16) | (q[15]<<24);
    *reinterpret_cast<int4*>(xq + j * 16) = d;
}

__global__ __launch_bounds__(256) void cvt_w_pack(const int* __restrict__ w,
                                                  char* __restrict__ wq) {
    size_t j = (size_t)blockIdx.x * 256 + threadIdx.x;
    int nt = (int)(j >> 16);
    int j2 = (int)(j & 65535);
    int kt = j2 >> 10;
    int f  = (j2 >> 6) & 15;
    int l  = j2 & 63;
    int r  = nt * 256 + f * 16 + (l & 15);
    int k0 = kt * 64 + ((l >> 4) << 4);
    const int4* s = reinterpret_cast<const int4*>(w + (size_t)r * K_TOTAL + k0);
    int4 v0 = s[0], v1 = s[1], v2 = s[2], v3 = s[3];
    int4 d;
    d.x = (v0.x&0xff) | ((v0.y&0xff)<<8) | ((v0.z&0xff)<<16) | (v0.w<<24);
    d.y = (v1.x&0xff) | ((v1.y&0xff)<<8) | ((v1.z&0xff)<<16) | (v1.w<<24);
    d.z = (v2.x&0xff) | ((v2.y&0xff)<<8) | ((v2.z&0xff)<<16) | (v2.w<<24);
    d.w = (v3.x&0xff) | ((v3.y&0xff)<<8) | ((v3.z&0xff)<<16) | (v3.w<<24);
    *reinterpret_cast<int4*>(wq + j * 16) = d;
}

// ---------------- GEMM: i8, 256-thread blocks (4 waves), 2 blocks/CU ----------------
// Same window schedule as round 14/15 (functionally verified): window w
// (set s=w&1): STG(tile w+2 -> buf w&1); 12 ds_reads of tile w+1 <- buf
// (w+1)&1 into set ~s; 32 mfma per wave on set s; LGKM0; VMC0; BAR.
// The experiment: block = 4 waves, BN=128, LDS 48KB -> TWO barrier-
// independent blocks co-resident per CU at the same 8 waves/CU (256 unified
// regs/wave caps at 8 waves). One block's MFMA cluster overlaps the other's
// LDS bursts (m97/m114 cross-block mechanism) -- no intra-block scheduling
// finesse required. NOTE: launch_bounds min-waves rider REMOVED (round 15:
// (512,4) forced 64 VGPR -> acc spilled -> 29GB scratch writes, 14x slower).

#define BAR()    { asm volatile("" ::: "memory"); __builtin_amdgcn_s_barrier(); asm volatile("" ::: "memory"); }
#define LGKM0()  asm volatile("s_waitcnt lgkmcnt(0)" ::: "memory")
#define VMC6()   asm volatile("s_waitcnt vmcnt(6)" ::: "memory")
#define VMC0()   asm volatile("s_waitcnt vmcnt(0)" ::: "memory")
#define PRIO1()  __builtin_amdgcn_s_setprio(1)
#define PRIO0()  __builtin_amdgcn_s_setprio(0)
#define SCHEDB() __builtin_amdgcn_sched_barrier(0)

// A: 16KB/kt (4 x 4KB ops); B: 8KB half-block slice (2 x 4KB ops)
#define STG(ts, so) { \
    async16(aS + (size_t)(ts)*TILE_B + tid*16,         ldsc + (so) + tid*16); \
    async16(aS + (size_t)(ts)*TILE_B + 4096 + tid*16,  ldsc + (so) + 4096 + tid*16); \
    async16(aS + (size_t)(ts)*TILE_B + 8192 + tid*16,  ldsc + (so) + 8192 + tid*16); \
    async16(aS + (size_t)(ts)*TILE_B + 12288 + tid*16, ldsc + (so) + 12288 + tid*16); \
    async16(bS + (size_t)(ts)*TILE_B + tid*16,         ldsc + (so) + 16384 + tid*16); \
    async16(bS + (size_t)(ts)*TILE_B + 4096 + tid*16,  ldsc + (so) + 20480 + tid*16); }

#define RDF0(bo) { \
    _Pragma("unroll") for (int ni = 0; ni < 4; ++ni) bfr0[ni] = *(const i32x4*)(bRd + (bo) + ni * 1024); \
    _Pragma("unroll") for (int mi = 0; mi < 8; ++mi) afr0[mi] = *(const i32x4*)(aRd + (bo) + mi * 1024); }

#define RDF1(bo) { \
    _Pragma("unroll") for (int ni = 0; ni < 4; ++ni) bfr1[ni] = *(const i32x4*)(bRd + (bo) + ni * 1024); \
    _Pragma("unroll") for (int mi = 0; mi < 8; ++mi) afr1[mi] = *(const i32x4*)(aRd + (bo) + mi * 1024); }

#define MMA0() { PRIO1(); \
    _Pragma("unroll") for (int mi = 0; mi < 8; ++mi) { _Pragma("unroll") \
        for (int ni = 0; ni < 4; ++ni) \
            acc[mi][ni] = __builtin_amdgcn_mfma_i32_16x16x64_i8(afr0[mi], bfr0[ni], acc[mi][ni], 0, 0, 0); } \
    PRIO0(); }

#define MMA1() { PRIO1(); \
    _Pragma("unroll") for (int mi = 0; mi < 8; ++mi) { _Pragma("unroll") \
        for (int ni = 0; ni < 4; ++ni) \
            acc[mi][ni] = __builtin_amdgcn_mfma_i32_16x16x64_i8(afr1[mi], bfr1[ni], acc[mi][ni], 0, 0, 0); } \
    PRIO0(); }

#define WIN(st, sb, rb, RDFx, MMAx) { \
    STG(st, sb); \
    RDFx(rb); \
    SCHEDB(); \
    MMAx(); \
    SCHEDB(); \
    LGKM0(); VMC0(); BAR(); }

__global__ __launch_bounds__(256, 2) void gemm_kernel(const char* __restrict__ A,
                                                      const char* __restrict__ B,
                                                      const float* __restrict__ scale,
                                                      const float* __restrict__ sx,
                                                      float* __restrict__ out) {
    extern __shared__ char ldsc[];
    const int tid  = threadIdx.x;
    const int lane = tid & 63;
    const int wave = tid >> 6;         // 0..3
    const int wm = wave >> 1;          // 0..1 (128 rows each)
    const int wn = wave & 1;           // 0..1 (64 cols each)

    // XCD-aware bijective swizzle (4096 blocks, 8 XCDs, 512-block chunks);
    // mt fastest within chunk -> co-resident blocks/XCD share B-panels.
    int orig = blockIdx.x;
    int swzid = (orig & 7) * 512 + (orig >> 3);
    int mt  = swzid & 31;              // 0..31  (M tiles of 256)
    int nt2 = swzid >> 5;              // 0..127 (N tiles of 128)

    const char* aS = A + (size_t)mt * (KT * TILE_B);
    // B: half of 256-row block (nt2>>1); halves split as f 0..7 / 8..15
    const char* bS = B + (size_t)(nt2 >> 1) * (KT * TILE_B) + (size_t)(nt2 & 1) * 8192;

    // fragment read bases: stride-1 1KB wave reads (uniform base + lane*16)
    const char* aRd = ldsc + wm * 8192 + lane * 16;           // + bo + mi*1024
    const char* bRd = ldsc + 16384 + wn * 4096 + lane * 16;   // + bo + ni*1024

    i32x4 acc[8][4];
    #pragma unroll
    for (int mi = 0; mi < 8; ++mi)
        #pragma unroll
        for (int ni = 0; ni < 4; ++ni)
            acc[mi][ni] = (i32x4){0, 0, 0, 0};

    i32x4 afr0[8], bfr0[4], afr1[8], bfr1[4];

    // prologue: stage tile0->buf0, tile1->buf1; VMC6 certifies tile0 (tile1's
    // 6 loads in flight); BAR; read tile0 -> set0; LGKM0; VMC0 (tile1
    // certified); BAR.
    STG(0, 0); STG(1, BUF_S);
    VMC6();
    BAR();
    RDF0(0);
    LGKM0();
    VMC0();
    BAR();

    // windows 0..61 (stage tiles 2..63), unroll x2
    for (int w = 0; w < 62; w += 2) {
        WIN(w + 2, 0,     BUF_S, RDF1, MMA0);   // w even: stage->buf0, rd t+1<-buf1, mfma t
        WIN(w + 3, BUF_S, 0,     RDF0, MMA1);   // w odd:  stage->buf1, rd t+2<-buf0, mfma t+1
    }
    // window 62 (set0): rd tile 63 <- buf1; mfma 62.
    RDF1(BUF_S);
    SCHEDB();
    MMA0();
    SCHEDB();
    // window 63 (set1): mfma 63 (compiler waits on set1's reads).
    MMA1();

    // epilogue: D row=(lane>>4)*4+j, col=lane&15 (shape-determined);
    // out = acc * sx[row] * sw[col]
    int m0 = mt * BM, n0 = nt2 * BN;
    int col0 = n0 + wn * 64 + (lane & 15);
    int row0 = m0 + wm * 128 + ((lane >> 4) << 2);
    float swv[4];
    #pragma unroll
    for (int ni = 0; ni < 4; ++ni) swv[ni] = scale[col0 + ni * 16];
    #pragma unroll
    for (int mi = 0; mi < 8; ++mi) {
        #pragma unroll
        for (int j = 0; j < 4; ++j) {
            int r = row0 + mi * 16 + j;
            float sr = sx[r];
            #pragma unroll
            for (int ni = 0; ni < 4; ++ni) {
                out[(size_t)r * N_TOTAL + (col0 + ni * 16)] = (float)acc[mi][ni][j] * sr * swv[ni];
            }
        }
    }
}

// ---------------- fallback ----------------

__global__ __launch_bounds__(256) void naive_kernel(const float* __restrict__ x, const int* __restrict__ w,
                                                    const float* __restrict__ scale, float* __restrict__ out) {
    int n = blockIdx.x * 256 + threadIdx.x;
    int m = blockIdx.y;
    const float* xr = x + (size_t)m * K_TOTAL;
    const int*   wr = w + (size_t)n * K_TOTAL;
    float acc = 0.f;
    for (int k = 0; k < K_TOTAL; k += 4) {
        float4 xv = *(const float4*)(xr + k);
        int4   wv = *(const int4*)(wr + k);
        acc += xv.x * (float)wv.x + xv.y * (float)wv.y + xv.z * (float)wv.z + xv.w * (float)wv.w;
    }
    out[(size_t)m * N_TOTAL + n] = acc * scale[n];
}

extern "C" void kernel_launch(void* const* d_in, const int* in_sizes, int n_in,
                              void* d_out, int out_size, void* d_ws, size_t ws_size,
                              hipStream_t stream) {
    const float* x     = (const float*)d_in[0];
    const int*   w     = (const int*)d_in[1];
    const float* scale = (const float*)d_in[2];
    float* out = (float*)d_out;

    const size_t xq_bytes = (size_t)M_TOTAL * K_TOTAL;       // 32MB
    const size_t wq_bytes = (size_t)N_TOTAL * K_TOTAL;       // 64MB
    const size_t sx_bytes = (size_t)M_TOTAL * 4;             // 32KB

    if (ws_size >= xq_bytes + wq_bytes + 2 * sx_bytes) {
        char*  xq   = (char*)d_ws;
        char*  wq   = (char*)d_ws + xq_bytes;
        float* sx   = (float*)((char*)d_ws + xq_bytes + wq_bytes);
        float* invx = sx + M_TOTAL;
        (void)hipFuncSetAttribute((const void*)gemm_kernel,
                                  hipFuncAttributeMaxDynamicSharedMemorySize, NBUF * BUF_S);
        rowmax_kernel<<<M_TOTAL / 4, 256, 0, stream>>>(x, sx, invx);
        cvt_x_pack<<<(M_TOTAL / 256) * (K_TOTAL / 16) , 256, 0, stream>>>(x, invx, xq);
        cvt_w_pack<<<(N_TOTAL / 256) * (K_TOTAL / 16), 256, 0, stream>>>(w, wq);
        gemm_kernel<<<(M_TOTAL / BM) * (N_TOTAL / BN), 256, NBUF * BUF_S, stream>>>(xq, wq, scale, sx, out);
    } else {
        dim3 g(N_TOTAL / 256, M_TOTAL);
        naive_kernel<<<g, 256, 0, stream>>>(x, w, scale, out);
    }
}

// Round 17
// 738.620 us; speedup vs baseline: 11.8192x; 1.1720x over previous
//
#include <hip/hip_runtime.h>
#include <hip/hip_bf16.h>
#include <stdint.h>

#define M_TOTAL 8192
#define K_TOTAL 4096
#define N_TOTAL 16384
#define BM 256
#define BN 256
#define KT 64                          // 64 K-tiles of 64 (i8: one MFMA eats K=64)
#define TILE_B 16384                   // bytes per 256-row block per K-tile (256 x 64 x 1B)
#define BUF_S 32768                    // LDS buffer: A 16KB + B 16KB
#define NBUF 4

typedef int i32x4 __attribute__((ext_vector_type(4)));

static __device__ __forceinline__ void async16(const void* g, void* l) {
    __builtin_amdgcn_global_load_lds((const __attribute__((address_space(1))) unsigned int*)g,
                                     (__attribute__((address_space(3))) unsigned int*)l,
                                     16, 0, 0);
}

// ---------------- packing kernels ----------------
// Packed i8 layout per 256-row block (1MB): [kt 0..63][f 0..15][lane 0..63][16B]
// element (row, k): f=(row>>4)&15, lane=(row&15)|(((k>>4)&3)<<4), byte=k&15.
// (verified by rounds 13/14, absmax 4.5)

// Fused rowmax + quantize + pack: one wave per row. The row (4096 f32 = 16KB)
// lives entirely in 64 VGPRs (16 float4/lane); absmax via 64-lane butterfly;
// quantize+pack from registers -> saves a full second HBM read of x and one
// kernel launch vs the separate rowmax pass.
__global__ __launch_bounds__(256) void cvt_x_fused(const float* __restrict__ x,
                                                   char* __restrict__ xq,
                                                   float* __restrict__ sx) {
    int r = blockIdx.x * 4 + (threadIdx.x >> 6);
    int l = threadIdx.x & 63;
    const float4* p = reinterpret_cast<const float4*>(x + (size_t)r * K_TOTAL) + l;
    float4 v[16];
    float m = 0.f;
    #pragma unroll
    for (int i = 0; i < 16; ++i) {
        v[i] = p[i * 64];
        m = fmaxf(m, fmaxf(fmaxf(fabsf(v[i].x), fabsf(v[i].y)), fmaxf(fabsf(v[i].z), fabsf(v[i].w))));
    }
    #pragma unroll
    for (int off = 32; off; off >>= 1) m = fmaxf(m, __shfl_xor(m, off, 64));
    m = fmaxf(m, 1e-20f);
    if (l == 0) sx[r] = m / 127.f;
    float inv = 127.f / m;

    // output addressing: k0 = 4*(l + 64*i); kt=(l>>4)+4*i; lane_p=(r&15)|(((l>>2)&3)<<4);
    // f=(r>>4)&15; byte-in-chunk = 4*(l&3)
    char* base = xq + (size_t)(r >> 8) * (KT * TILE_B)
               + ((r >> 4) & 15) * 1024
               + (((r & 15) | (((l >> 2) & 3) << 4)) * 16)
               + ((l & 3) << 2)
               + ((l >> 4) * 16384);
    #pragma unroll
    for (int i = 0; i < 16; ++i) {
        int q0 = (int)__builtin_rintf(v[i].x * inv);
        int q1 = (int)__builtin_rintf(v[i].y * inv);
        int q2 = (int)__builtin_rintf(v[i].z * inv);
        int q3 = (int)__builtin_rintf(v[i].w * inv);
        int wv = (q0 & 0xff) | ((q1 & 0xff) << 8) | ((q2 & 0xff) << 16) | (q3 << 24);
        *reinterpret_cast<int*>(base + (size_t)i * 4 * 16384) = wv;
    }
}

__global__ __launch_bounds__(256) void cvt_w_pack(const int* __restrict__ w,
                                                  char* __restrict__ wq) {
    size_t j = (size_t)blockIdx.x * 256 + threadIdx.x;
    int nt = (int)(j >> 16);
    int j2 = (int)(j & 65535);
    int kt = j2 >> 10;
    int f  = (j2 >> 6) & 15;
    int l  = j2 & 63;
    int r  = nt * 256 + f * 16 + (l & 15);
    int k0 = kt * 64 + ((l >> 4) << 4);
    const int4* s = reinterpret_cast<const int4*>(w + (size_t)r * K_TOTAL + k0);
    int4 v0 = s[0], v1 = s[1], v2 = s[2], v3 = s[3];
    int4 d;
    d.x = (v0.x&0xff) | ((v0.y&0xff)<<8) | ((v0.z&0xff)<<16) | (v0.w<<24);
    d.y = (v1.x&0xff) | ((v1.y&0xff)<<8) | ((v1.z&0xff)<<16) | (v1.w<<24);
    d.z = (v2.x&0xff) | ((v2.y&0xff)<<8) | ((v2.z&0xff)<<16) | (v2.w<<24);
    d.w = (v3.x&0xff) | ((v3.y&0xff)<<8) | ((v3.z&0xff)<<16) | (v3.w<<24);
    *reinterpret_cast<int4*>(wq + j * 16) = d;
}

// ---------------- GEMM: round-14 exact (best verified: 617us, absmax 4.5) ----------------
// Window w (set s = w&1): STG(tile w+2+... -> rotating buf); 12 ds_reads of
// tile w+1 -> set ~s; 32 mfma_i32_16x16x64_i8 on set s; vmcnt(4); barrier.
// No lgkm drain: reads retire lazily under next window's MFMA via compiler-
// counted lgkm waits. Buf read at w is overwritten at w+2 (after w+1's bar).

#define BAR()    { asm volatile("" ::: "memory"); __builtin_amdgcn_s_barrier(); asm volatile("" ::: "memory"); }
#define VMC4()   asm volatile("s_waitcnt vmcnt(4)" ::: "memory")
#define VMC0()   asm volatile("s_waitcnt vmcnt(0)" ::: "memory")
#define PRIO1()  __builtin_amdgcn_s_setprio(1)
#define PRIO0()  __builtin_amdgcn_s_setprio(0)
#define SCHEDB() __builtin_amdgcn_sched_barrier(0)

#define STG(ts, so) { \
    async16(aS + (size_t)(ts)*TILE_B + tid*16,        ldsc + (so) + tid*16); \
    async16(aS + (size_t)(ts)*TILE_B + 8192 + tid*16, ldsc + (so) + 8192 + tid*16); \
    async16(bS + (size_t)(ts)*TILE_B + tid*16,        ldsc + (so) + 16384 + tid*16); \
    async16(bS + (size_t)(ts)*TILE_B + 8192 + tid*16, ldsc + (so) + 24576 + tid*16); }

#define RDF0(bo) { \
    _Pragma("unroll") for (int ni = 0; ni < 4; ++ni) bfr0[ni] = *(const i32x4*)(bRd + (bo) + ni * 1024); \
    _Pragma("unroll") for (int mi = 0; mi < 8; ++mi) afr0[mi] = *(const i32x4*)(aRd + (bo) + mi * 1024); }

#define RDF1(bo) { \
    _Pragma("unroll") for (int ni = 0; ni < 4; ++ni) bfr1[ni] = *(const i32x4*)(bRd + (bo) + ni * 1024); \
    _Pragma("unroll") for (int mi = 0; mi < 8; ++mi) afr1[mi] = *(const i32x4*)(aRd + (bo) + mi * 1024); }

#define MMA0() { PRIO1(); \
    _Pragma("unroll") for (int mi = 0; mi < 8; ++mi) { _Pragma("unroll") \
        for (int ni = 0; ni < 4; ++ni) \
            acc[mi][ni] = __builtin_amdgcn_mfma_i32_16x16x64_i8(afr0[mi], bfr0[ni], acc[mi][ni], 0, 0, 0); } \
    PRIO0(); }

#define MMA1() { PRIO1(); \
    _Pragma("unroll") for (int mi = 0; mi < 8; ++mi) { _Pragma("unroll") \
        for (int ni = 0; ni < 4; ++ni) \
            acc[mi][ni] = __builtin_amdgcn_mfma_i32_16x16x64_i8(afr1[mi], bfr1[ni], acc[mi][ni], 0, 0, 0); } \
    PRIO0(); }

#define WIN(st, sb, rb, RDFx, MMAx) { \
    STG(st, sb); \
    RDFx(rb); \
    SCHEDB(); \
    MMAx(); \
    SCHEDB(); \
    VMC4(); BAR(); }

__global__ __launch_bounds__(512, 2) void gemm_kernel(const char* __restrict__ A,
                                                      const char* __restrict__ B,
                                                      const float* __restrict__ scale,
                                                      const float* __restrict__ sx,
                                                      float* __restrict__ out) {
    extern __shared__ char ldsc[];
    const int tid  = threadIdx.x;
    const int lane = tid & 63;
    const int wave = tid >> 6;
    const int wm = wave >> 2;          // 0..1
    const int wn = wave & 3;           // 0..3

    // XCD-aware bijective swizzle (2048 blocks, 8 XCDs, 256-block chunks);
    // mt fastest within chunk -> 32 co-resident blocks/XCD share one B-panel.
    int orig = blockIdx.x;
    int swzid = (orig & 7) * 256 + (orig >> 3);
    int mt = swzid & 31;
    int nt = swzid >> 5;

    const char* aS = A + (size_t)mt * (KT * TILE_B);
    const char* bS = B + (size_t)nt * (KT * TILE_B);

    // fragment read bases: stride-1 1KB wave reads (uniform base + lane*16)
    const char* aRd = ldsc + wm * 8192 + lane * 16;           // + bo + mi*1024
    const char* bRd = ldsc + 16384 + wn * 4096 + lane * 16;   // + bo + ni*1024

    i32x4 acc[8][4];
    #pragma unroll
    for (int mi = 0; mi < 8; ++mi)
        #pragma unroll
        for (int ni = 0; ni < 4; ++ni)
            acc[mi][ni] = (i32x4){0, 0, 0, 0};

    i32x4 afr0[8], bfr0[4], afr1[8], bfr1[4];

    // prologue: stage tiles 0,1,2 -> bufs 0,1,2; VMC4 drains stages 0,1;
    // barrier; read tile 0 -> set0.
    STG(0, 0); STG(1, BUF_S); STG(2, 2 * BUF_S);
    VMC4();
    BAR();
    RDF0(0);

    // windows 0..59 (stage tiles 3..62), unroll x4 for static LDS offsets
    for (int T = 0; T < 60; T += 4) {
        WIN(T + 3, 3 * BUF_S, 1 * BUF_S, RDF1, MMA0);   // w=T:   mfma T,   rd T+1
        WIN(T + 4, 0,         2 * BUF_S, RDF0, MMA1);   // w=T+1: mfma T+1, rd T+2
        WIN(T + 5, 1 * BUF_S, 3 * BUF_S, RDF1, MMA0);   // w=T+2: mfma T+2, rd T+3
        WIN(T + 6, 2 * BUF_S, 0,         RDF0, MMA1);   // w=T+3: mfma T+3, rd T+4
    }
    // window 60 (set0): stage tile 63 -> buf3; rd tile 61 <- buf1; mfma 60.
    WIN(63, 3 * BUF_S, 1 * BUF_S, RDF1, MMA0);
    // window 61 (set1): rd tile 62 <- buf2; mfma 61; VMC0 certifies tile 63.
    RDF0(2 * BUF_S);
    SCHEDB();
    MMA1();
    SCHEDB();
    VMC0(); BAR();
    // window 62 (set0): rd tile 63 <- buf3; mfma 62.
    RDF1(3 * BUF_S);
    SCHEDB();
    MMA0();
    SCHEDB();
    // window 63 (set1): mfma 63 (compiler waits on set1's reads).
    MMA1();

    // epilogue: D row=(lane>>4)*4+j, col=lane&15; out = acc * sx[row] * sw[col]
    int m0 = mt * BM, n0 = nt * BN;
    int col0 = n0 + wn * 64 + (lane & 15);
    int row0 = m0 + wm * 128 + ((lane >> 4) << 2);
    float swv[4];
    #pragma unroll
    for (int ni = 0; ni < 4; ++ni) swv[ni] = scale[col0 + ni * 16];
    #pragma unroll
    for (int mi = 0; mi < 8; ++mi) {
        #pragma unroll
        for (int j = 0; j < 4; ++j) {
            int r = row0 + mi * 16 + j;
            float sr = sx[r];
            #pragma unroll
            for (int ni = 0; ni < 4; ++ni) {
                out[(size_t)r * N_TOTAL + (col0 + ni * 16)] = (float)acc[mi][ni][j] * sr * swv[ni];
            }
        }
    }
}

// ---------------- fallback ----------------

__global__ __launch_bounds__(256) void naive_kernel(const float* __restrict__ x, const int* __restrict__ w,
                                                    const float* __restrict__ scale, float* __restrict__ out) {
    int n = blockIdx.x * 256 + threadIdx.x;
    int m = blockIdx.y;
    const float* xr = x + (size_t)m * K_TOTAL;
    const int*   wr = w + (size_t)n * K_TOTAL;
    float acc = 0.f;
    for (int k = 0; k < K_TOTAL; k += 4) {
        float4 xv = *(const float4*)(xr + k);
        int4   wv = *(const int4*)(wr + k);
        acc += xv.x * (float)wv.x + xv.y * (float)wv.y + xv.z * (float)wv.z + xv.w * (float)wv.w;
    }
    out[(size_t)m * N_TOTAL + n] = acc * scale[n];
}

extern "C" void kernel_launch(void* const* d_in, const int* in_sizes, int n_in,
                              void* d_out, int out_size, void* d_ws, size_t ws_size,
                              hipStream_t stream) {
    const float* x     = (const float*)d_in[0];
    const int*   w     = (const int*)d_in[1];
    const float* scale = (const float*)d_in[2];
    float* out = (float*)d_out;

    const size_t xq_bytes = (size_t)M_TOTAL * K_TOTAL;       // 32MB
    const size_t wq_bytes = (size_t)N_TOTAL * K_TOTAL;       // 64MB
    const size_t sx_bytes = (size_t)M_TOTAL * 4;             // 32KB

    if (ws_size >= xq_bytes + wq_bytes + sx_bytes) {
        char*  xq = (char*)d_ws;
        char*  wq = (char*)d_ws + xq_bytes;
        float* sx = (float*)((char*)d_ws + xq_bytes + wq_bytes);
        (void)hipFuncSetAttribute((const void*)gemm_kernel,
                                  hipFuncAttributeMaxDynamicSharedMemorySize, NBUF * BUF_S);
        cvt_x_fused<<<M_TOTAL / 4, 256, 0, stream>>>(x, xq, sx);
        cvt_w_pack<<<(N_TOTAL / 256) * (K_TOTAL / 16), 256, 0, stream>>>(w, wq);
        gemm_kernel<<<(M_TOTAL / BM) * (N_TOTAL / BN), 512, NBUF * BUF_S, stream>>>(xq, wq, scale, sx, out);
    } else {
        dim3 g(N_TOTAL / 256, M_TOTAL);
        naive_kernel<<<g, 256, 0, stream>>>(x, w, scale, out);
    }
}